// Round 1
// baseline (118.803 us; speedup 1.0000x reference)
//
#include <hip/hip_runtime.h>
#include <hip/hip_bf16.h>
#include <stdint.h>

// ItemEncoder: h = relu(concat(emb[type], item) @ W + b); out = max over item axis.
// BS=32, NA=128, NI=128, F=11, TH=32, K=43 (pad->64), NH=128.
// One block per (b,n): builds A(128x64 f16, gathered+concat) and B(W^T 128x64 f16)
// in XOR-swizzled LDS, 4 waves x 16 mfma_f32_32x32x16_f16, max-reduce epilogue.

#define NITEM 128
#define NFEAT 11
#define NTH   32
#define NH    128
#define KDIM  64
#define KREAL 43

typedef __attribute__((ext_vector_type(8))) _Float16 half8;
typedef __attribute__((ext_vector_type(16))) float   f32x16;

__global__ __launch_bounds__(256, 4) void item_encoder(
    const int*   __restrict__ item_type,  // [BS*NA*NI] int32
    const float* __restrict__ item,       // [BS*NA*NI*NFEAT]
    const float* __restrict__ emb,        // [18*32]
    const float* __restrict__ W,          // [43*128] (row-major, f-major)
    const float* __restrict__ bias,       // [128]
    float*       __restrict__ out)        // [BS*NA*NH]
{
    __shared__ _Float16 Alds[NITEM][KDIM];   // 16 KB, 16B blocks swizzled by ^(row&7)
    __shared__ _Float16 Blds[NH][KDIM];      // 16 KB, W^T, same swizzle
    __shared__ float    partial[4][NH];      // 2 KB

    const int bn = blockIdx.x;      // 0..4095
    const int t  = threadIdx.x;     // 0..255

    const int*   tyrow = item_type + bn * NITEM;
    const float* itrow = item + (size_t)bn * NITEM * NFEAT;

    // ---- build A tile: row = item index, k = 0..31 emb gather, 32..42 feats, rest 0 ----
    #pragma unroll
    for (int j = 0; j < 4; ++j) {
        const int idx = t + 256 * j;        // 0..1023 = 128 rows x 8 k-blocks
        const int row = idx >> 3;
        const int kb  = idx & 7;            // 16B block (8 f16) within row
        float v[8];
        if (kb < 4) {
            const int ty = tyrow[row];
            const float* e = emb + ty * NTH + kb * 8;
            #pragma unroll
            for (int q = 0; q < 8; ++q) v[q] = e[q];
        } else if (kb == 4) {
            const float* p = itrow + row * NFEAT;
            #pragma unroll
            for (int q = 0; q < 8; ++q) v[q] = p[q];
        } else if (kb == 5) {
            const float* p = itrow + row * NFEAT + 8;
            #pragma unroll
            for (int q = 0; q < 8; ++q) v[q] = (q < 3) ? p[q] : 0.0f;
        } else {
            #pragma unroll
            for (int q = 0; q < 8; ++q) v[q] = 0.0f;
        }
        half8 pk;
        #pragma unroll
        for (int q = 0; q < 8; ++q) pk[q] = (_Float16)v[q];
        ((half8*)&Alds[row][0])[kb ^ (row & 7)] = pk;
    }

    // ---- build B tile: B[col][k] = W[k][col] (k >= 43 -> 0) ----
    #pragma unroll
    for (int j = 0; j < 4; ++j) {
        const int idx = t + 256 * j;
        const int col = idx >> 3;
        const int kb  = idx & 7;
        float v[8];
        #pragma unroll
        for (int q = 0; q < 8; ++q) {
            const int k = kb * 8 + q;
            v[q] = (k < KREAL) ? W[k * NH + col] : 0.0f;
        }
        half8 pk;
        #pragma unroll
        for (int q = 0; q < 8; ++q) pk[q] = (_Float16)v[q];
        ((half8*)&Blds[col][0])[kb ^ (col & 7)] = pk;
    }

    __syncthreads();

    // ---- MFMA: wave w owns item rows [w*32, w*32+32), all 128 output cols ----
    const int lane = t & 63;
    const int w    = t >> 6;
    const int l31  = lane & 31;
    const int lhi  = lane >> 5;      // k-half selector

    f32x16 acc[4];
    #pragma unroll
    for (int n = 0; n < 4; ++n)
        #pragma unroll
        for (int r = 0; r < 16; ++r) acc[n][r] = 0.0f;

    const int arow = w * 32 + l31;
    #pragma unroll
    for (int kk = 0; kk < 4; ++kk) {         // K = 4 x 16
        const int blk = kk * 2 + lhi;        // 16B block index along k
        const half8 af = ((const half8*)&Alds[arow][0])[blk ^ (arow & 7)];
        #pragma unroll
        for (int n = 0; n < 4; ++n) {
            const int bcol = n * 32 + l31;
            const half8 bfr = ((const half8*)&Blds[bcol][0])[blk ^ (bcol & 7)];
            acc[n] = __builtin_amdgcn_mfma_f32_32x32x16_f16(af, bfr, acc[n], 0, 0, 0);
        }
    }

    // ---- epilogue: max over the wave's 32 item-rows, +bias, relu ----
    // C/D layout: col = lane&31, row = (reg&3) + 8*(reg>>2) + 4*(lane>>5)
    #pragma unroll
    for (int n = 0; n < 4; ++n) {
        float m = acc[n][0];
        #pragma unroll
        for (int r = 1; r < 16; ++r) m = fmaxf(m, acc[n][r]);
        m = fmaxf(m, __shfl_xor(m, 32));              // combine lane-hi halves (all 32 rows)
        m = fmaxf(m + bias[n * 32 + l31], 0.0f);
        if (lane < 32) partial[w][n * 32 + l31] = m;
    }

    __syncthreads();

    if (t < NH) {
        float m = fmaxf(fmaxf(partial[0][t], partial[1][t]),
                        fmaxf(partial[2][t], partial[3][t]));
        out[(size_t)bn * NH + t] = m;
    }
}

extern "C" void kernel_launch(void* const* d_in, const int* in_sizes, int n_in,
                              void* d_out, int out_size, void* d_ws, size_t ws_size,
                              hipStream_t stream) {
    const int*   item_type = (const int*)  d_in[0];
    const float* item      = (const float*)d_in[1];
    const float* emb       = (const float*)d_in[2];
    const float* W         = (const float*)d_in[3];
    const float* bias      = (const float*)d_in[4];
    float*       out       = (float*)d_out;

    const int nblocks = 32 * 128;   // BS * NA
    item_encoder<<<nblocks, 256, 0, stream>>>(item_type, item, emb, W, bias, out);
}

// Round 2
// 95.745 us; speedup vs baseline: 1.2408x; 1.2408x over previous
//
#include <hip/hip_runtime.h>
#include <hip/hip_bf16.h>
#include <stdint.h>

// ItemEncoder: h = relu(concat(emb[type], item) @ W + b); out = max over item axis.
// BS=32, NA=128, NI=128, F=11, TH=32, K=43 (pad->48), NH=128.
//
// R2 structure:
//  - prep_b pre-kernel: W (43x128 f32) -> f16 MFMA B-fragments in d_ws (12 KB),
//    laid out so the main kernel's loads are fully coalesced. Kills the per-block
//    strided W rebuild that dominated R1 (~50 us of scattered L1 loads).
//  - main kernel: one block per (b,n). A-tile (128x48 f16) gathered+concat into
//    XOR-swizzled LDS with wave-uniform branches; B held in registers;
//    12x mfma_f32_32x32x16_f16 per wave (K=48); max/bias/relu epilogue.

#define NITEM 128
#define NFEAT 11
#define NTH   32
#define NH    128
#define KREAL 43
#define KSTEPS 3          // K = 48 = 3 x 16

typedef __attribute__((ext_vector_type(8))) _Float16 half8;
typedef __attribute__((ext_vector_type(16))) float   f32x16;

// ---- pre-kernel: build B fragments (frag = kk*4+n, 64 lanes each, half8/lane) ----
__global__ __launch_bounds__(64) void prep_b(const float* __restrict__ W,
                                             _Float16* __restrict__ Bpre) {
    const int frag = blockIdx.x;          // 0..11 = kk*4 + n
    const int kk   = frag >> 2;
    const int n    = frag & 3;
    const int lane = threadIdx.x;         // 0..63
    const int col  = n * 32 + (lane & 31);
    const int k0   = kk * 16 + (lane >> 5) * 8;
    half8 pk;
    #pragma unroll
    for (int q = 0; q < 8; ++q) {
        const int k = k0 + q;
        pk[q] = (_Float16)((k < KREAL) ? W[k * NH + col] : 0.0f);
    }
    ((half8*)Bpre)[frag * 64 + lane] = pk;
}

__global__ __launch_bounds__(256, 3) void item_encoder(
    const int*      __restrict__ item_type,  // [BS*NA*NI] int32
    const float*    __restrict__ item,       // [BS*NA*NI*NFEAT]
    const float*    __restrict__ emb,        // [18*32]
    const _Float16* __restrict__ Bpre,       // [12*64*8] f16 frags
    const float*    __restrict__ bias,       // [128]
    float*          __restrict__ out)        // [BS*NA*NH]
{
    __shared__ _Float16 Alds[NITEM][64];     // 16 KB; 16B blocks, swizzle ^(row&7); blocks 6,7 unused
    __shared__ float    partial[4][NH];      // 2 KB

    const int bn   = blockIdx.x;             // 0..4095
    const int t    = threadIdx.x;            // 0..255
    const int lane = t & 63;
    const int w    = t >> 6;
    const int l31  = lane & 31;
    const int lhi  = lane >> 5;

    // ---- B fragments from ws: 12 coalesced 16B loads/lane ----
    half8 bf[KSTEPS][4];
    #pragma unroll
    for (int kk = 0; kk < KSTEPS; ++kk)
        #pragma unroll
        for (int n = 0; n < 4; ++n)
            bf[kk][n] = ((const half8*)Bpre)[(kk * 4 + n) * 64 + lane];

    const int*   tyrow = item_type + bn * NITEM;
    const float* itrow = item + (size_t)bn * NITEM * NFEAT;

    // ---- build A tile: idx = j*256+t -> kb = idx>>7 (wave-uniform), row = idx&127 ----
    // k layout per row: [0,32) = emb[type], [32,43) = item feats, [43,48) = 0
    #pragma unroll
    for (int j = 0; j < 3; ++j) {
        const int idx = j * 256 + t;
        const int kb  = idx >> 7;            // 16B block along k; uniform per wave
        const int row = idx & 127;
        half8 pk;
        if (kb < 4) {                        // emb gather, 32B/lane from 2.3KB table
            const int    ty = tyrow[row];
            const float4 e0 = *(const float4*)(emb + ty * NTH + kb * 8);
            const float4 e1 = *(const float4*)(emb + ty * NTH + kb * 8 + 4);
            pk[0] = (_Float16)e0.x; pk[1] = (_Float16)e0.y;
            pk[2] = (_Float16)e0.z; pk[3] = (_Float16)e0.w;
            pk[4] = (_Float16)e1.x; pk[5] = (_Float16)e1.y;
            pk[6] = (_Float16)e1.z; pk[7] = (_Float16)e1.w;
        } else if (kb == 4) {                // item feats 0..7
            const float* p = itrow + row * NFEAT;
            #pragma unroll
            for (int q = 0; q < 8; ++q) pk[q] = (_Float16)p[q];
        } else {                             // kb == 5: feats 8..10 + zero pad
            const float* p = itrow + row * NFEAT + 8;
            #pragma unroll
            for (int q = 0; q < 8; ++q) pk[q] = (_Float16)((q < 3) ? p[q] : 0.0f);
        }
        ((half8*)&Alds[row][0])[kb ^ (row & 7)] = pk;
    }

    __syncthreads();

    // ---- MFMA: wave w owns item rows [w*32, w*32+32), all 128 cols ----
    f32x16 acc[4];
    #pragma unroll
    for (int n = 0; n < 4; ++n)
        #pragma unroll
        for (int r = 0; r < 16; ++r) acc[n][r] = 0.0f;

    const int arow = w * 32 + l31;
    #pragma unroll
    for (int kk = 0; kk < KSTEPS; ++kk) {
        const int blk = kk * 2 + lhi;
        const half8 af = ((const half8*)&Alds[arow][0])[blk ^ (arow & 7)];
        #pragma unroll
        for (int n = 0; n < 4; ++n)
            acc[n] = __builtin_amdgcn_mfma_f32_32x32x16_f16(af, bf[kk][n], acc[n], 0, 0, 0);
    }

    // ---- epilogue: max over rows, +bias, relu ----
    // C/D layout: col = lane&31, row = (reg&3) + 8*(reg>>2) + 4*(lane>>5)
    #pragma unroll
    for (int n = 0; n < 4; ++n) {
        float m = acc[n][0];
        #pragma unroll
        for (int r = 1; r < 16; ++r) m = fmaxf(m, acc[n][r]);
        m = fmaxf(m, __shfl_xor(m, 32));     // fold the two 16-row halves
        m = fmaxf(m + bias[n * 32 + l31], 0.0f);
        if (lane < 32) partial[w][n * 32 + l31] = m;
    }

    __syncthreads();

    if (t < NH) {
        float m = fmaxf(fmaxf(partial[0][t], partial[1][t]),
                        fmaxf(partial[2][t], partial[3][t]));
        out[(size_t)bn * NH + t] = m;
    }
}

extern "C" void kernel_launch(void* const* d_in, const int* in_sizes, int n_in,
                              void* d_out, int out_size, void* d_ws, size_t ws_size,
                              hipStream_t stream) {
    const int*   item_type = (const int*)  d_in[0];
    const float* item      = (const float*)d_in[1];
    const float* emb       = (const float*)d_in[2];
    const float* W         = (const float*)d_in[3];
    const float* bias      = (const float*)d_in[4];
    float*       out       = (float*)d_out;
    _Float16*    Bpre      = (_Float16*)d_ws;   // 12*64*8*2 = 12 KB

    prep_b<<<12, 64, 0, stream>>>(W, Bpre);
    item_encoder<<<32 * 128, 256, 0, stream>>>(item_type, item, emb, Bpre, bias, out);
}

// Round 5
// 91.073 us; speedup vs baseline: 1.3045x; 1.0513x over previous
//
#include <hip/hip_runtime.h>
#include <hip/hip_bf16.h>
#include <stdint.h>

// ItemEncoder: h = relu(concat(emb[type], item) @ W + b); out = max over item axis.
// BS=32, NA=128, NI=128, F=11, TH=32, K=43 (pad->48), NH=128.
//
// R5 = R3 design, compile fix: cvt_pkrtz returns __fp16 ext_vector(2); union view
// retyped to match (same 32-bit storage feeding the half8 MFMA operand).
//  - prep_b: W -> f16 MFMA B-fragments in d_ws (12 KB), coalesced.
//  - item_encoder: 1024 blocks, 4 bn-groups per block.
//      phase 1: bulk-coalesced float4 staging of 4 item slabs (22.5 KB) + types (2 KB)
//               into LDS; ONE barrier. All global latency paid once, up front.
//      phase 2: per bn: lane builds its 3 A-frags in registers (emb gather from
//               L1-resident table, feats via stride-11 ds_read_b32 = conflict-free),
//               12x mfma_f32_32x32x16_f16, per-bn max/bias/relu into disjoint
//               partial[b] slots (no intermediate barriers).
//      phase 3: one barrier, cross-wave max, 2 coalesced stores/thread.

#define NITEM  128
#define NFEAT  11
#define NTH    32
#define NH     128
#define KREAL  43
#define KSTEPS 3            // K = 48 = 3 x 16
#define BNPB   4            // bn groups per block
#define SLABDW (NITEM * NFEAT)   // 1408 dwords per bn

typedef __attribute__((ext_vector_type(8)))  _Float16 half8;
typedef __attribute__((ext_vector_type(2)))  __fp16   fp16x2;   // cvt_pkrtz result type
typedef __attribute__((ext_vector_type(16))) float    f32x16;

union H8 { half8 h8; fp16x2 h2[4]; };

// ---- pre-kernel: build B fragments (frag = kk*4+n, 64 lanes each, half8/lane) ----
__global__ __launch_bounds__(64) void prep_b(const float* __restrict__ W,
                                             _Float16* __restrict__ Bpre) {
    const int frag = blockIdx.x;          // 0..11 = kk*4 + n
    const int kk   = frag >> 2;
    const int n    = frag & 3;
    const int lane = threadIdx.x;         // 0..63
    const int col  = n * 32 + (lane & 31);
    const int k0   = kk * 16 + (lane >> 5) * 8;
    half8 pk;
    #pragma unroll
    for (int q = 0; q < 8; ++q) {
        const int k = k0 + q;
        pk[q] = (_Float16)((k < KREAL) ? W[k * NH + col] : 0.0f);
    }
    ((half8*)Bpre)[frag * 64 + lane] = pk;
}

__global__ __launch_bounds__(256, 2) void item_encoder(
    const int*      __restrict__ item_type,  // [BS*NA*NI] int32
    const float*    __restrict__ item,       // [BS*NA*NI*NFEAT]
    const float*    __restrict__ emb,        // [18*32]
    const _Float16* __restrict__ Bpre,       // [12*64*8] f16 frags
    const float*    __restrict__ bias,       // [128]
    float*          __restrict__ out)        // [BS*NA*NH]
{
    __shared__ float slab[BNPB * SLABDW];        // 22528 B, raw f32 item feats
    __shared__ int   typs[BNPB * NITEM];         // 2048 B
    __shared__ float partial[BNPB][4][NH];       // 8192 B

    const int t    = threadIdx.x;                // 0..255
    const int lane = t & 63;
    const int w    = t >> 6;
    const int l31  = lane & 31;
    const int lhi  = lane >> 5;
    const int bn0  = blockIdx.x * BNPB;

    // ---- B fragments: 12 coalesced 16B loads/lane (L2-resident after first block) ----
    half8 bf[KSTEPS][4];
    #pragma unroll
    for (int kk = 0; kk < KSTEPS; ++kk)
        #pragma unroll
        for (int n = 0; n < 4; ++n)
            bf[kk][n] = ((const half8*)Bpre)[(kk * 4 + n) * 64 + lane];

    // ---- phase 1: bulk coalesced staging (4 slabs are contiguous in global) ----
    {
        const float4* gsl = (const float4*)(item + (size_t)bn0 * SLABDW);
        float4*       lsl = (float4*)slab;
        #pragma unroll
        for (int j = 0; j < 5; ++j) lsl[t + 256 * j] = gsl[t + 256 * j];  // 1280
        if (t < 128) lsl[1280 + t] = gsl[1280 + t];                       // 1408 total
        if (t < 128)
            ((int4*)typs)[t] = ((const int4*)(item_type + (size_t)bn0 * NITEM))[t];
    }
    __syncthreads();

    // ---- phase 2: per-bn compute; wave w owns item rows [w*32, w*32+32) ----
    const int r = w * 32 + l31;                  // this lane's item row (within bn)
    float bias4[4];
    #pragma unroll
    for (int n = 0; n < 4; ++n) bias4[n] = bias[n * 32 + l31];

    #pragma unroll 1
    for (int b = 0; b < BNPB; ++b) {
        const int    ty = typs[b * NITEM + r];
        const float* eb = emb + ty * NTH;

        // frags 0,1 from emb: k = kk*16 + lhi*8 + q  (q=0..7)
        const float4 e0 = *(const float4*)(eb + lhi * 8);
        const float4 e1 = *(const float4*)(eb + lhi * 8 + 4);
        const float4 e2 = *(const float4*)(eb + 16 + lhi * 8);
        const float4 e3 = *(const float4*)(eb + 16 + lhi * 8 + 4);

        H8 a0, a1, a2;
        a0.h2[0] = __builtin_amdgcn_cvt_pkrtz(e0.x, e0.y);
        a0.h2[1] = __builtin_amdgcn_cvt_pkrtz(e0.z, e0.w);
        a0.h2[2] = __builtin_amdgcn_cvt_pkrtz(e1.x, e1.y);
        a0.h2[3] = __builtin_amdgcn_cvt_pkrtz(e1.z, e1.w);
        a1.h2[0] = __builtin_amdgcn_cvt_pkrtz(e2.x, e2.y);
        a1.h2[1] = __builtin_amdgcn_cvt_pkrtz(e2.z, e2.w);
        a1.h2[2] = __builtin_amdgcn_cvt_pkrtz(e3.x, e3.y);
        a1.h2[3] = __builtin_amdgcn_cvt_pkrtz(e3.z, e3.w);

        // frag 2: features f = lhi*8 + q; f >= 11 -> 0 (stride-11 LDS reads, gcd(11,32)=1)
        const float* sp = slab + b * SLABDW + r * NFEAT;
        float fv[8];
        #pragma unroll
        for (int q = 0; q < 8; ++q) {
            const int f  = lhi * 8 + q;
            const bool ok = (f < NFEAT);
            const float x = sp[ok ? f : 0];          // clamp addr, mask value
            fv[q] = ok ? x : 0.0f;
        }
        a2.h2[0] = __builtin_amdgcn_cvt_pkrtz(fv[0], fv[1]);
        a2.h2[1] = __builtin_amdgcn_cvt_pkrtz(fv[2], fv[3]);
        a2.h2[2] = __builtin_amdgcn_cvt_pkrtz(fv[4], fv[5]);
        a2.h2[3] = __builtin_amdgcn_cvt_pkrtz(fv[6], fv[7]);

        f32x16 acc[4];
        #pragma unroll
        for (int n = 0; n < 4; ++n)
            #pragma unroll
            for (int rr = 0; rr < 16; ++rr) acc[n][rr] = 0.0f;

        #pragma unroll
        for (int n = 0; n < 4; ++n) acc[n] = __builtin_amdgcn_mfma_f32_32x32x16_f16(a0.h8, bf[0][n], acc[n], 0, 0, 0);
        #pragma unroll
        for (int n = 0; n < 4; ++n) acc[n] = __builtin_amdgcn_mfma_f32_32x32x16_f16(a1.h8, bf[1][n], acc[n], 0, 0, 0);
        #pragma unroll
        for (int n = 0; n < 4; ++n) acc[n] = __builtin_amdgcn_mfma_f32_32x32x16_f16(a2.h8, bf[2][n], acc[n], 0, 0, 0);

        // epilogue: max over this wave's 32 rows, +bias, relu -> partial[b][w]
        // C/D layout: col = lane&31, row = (reg&3) + 8*(reg>>2) + 4*(lane>>5)
        #pragma unroll
        for (int n = 0; n < 4; ++n) {
            float m = acc[n][0];
            #pragma unroll
            for (int rr = 1; rr < 16; ++rr) m = fmaxf(m, acc[n][rr]);
            m = fmaxf(m, __shfl_xor(m, 32));         // fold the two 16-row halves
            m = fmaxf(m + bias4[n], 0.0f);
            if (lane < 32) partial[b][w][n * 32 + l31] = m;
        }
    }

    __syncthreads();

    // ---- phase 3: cross-wave max + coalesced store (512 outputs / 256 threads) ----
    #pragma unroll
    for (int jj = 0; jj < 2; ++jj) {
        const int idx = t + 256 * jj;        // 0..511
        const int b   = idx >> 7;
        const int col = idx & 127;
        float m = fmaxf(fmaxf(partial[b][0][col], partial[b][1][col]),
                        fmaxf(partial[b][2][col], partial[b][3][col]));
        out[(size_t)(bn0 + b) * NH + col] = m;
    }
}

extern "C" void kernel_launch(void* const* d_in, const int* in_sizes, int n_in,
                              void* d_out, int out_size, void* d_ws, size_t ws_size,
                              hipStream_t stream) {
    const int*   item_type = (const int*)  d_in[0];
    const float* item      = (const float*)d_in[1];
    const float* emb       = (const float*)d_in[2];
    const float* W         = (const float*)d_in[3];
    const float* bias      = (const float*)d_in[4];
    float*       out       = (float*)d_out;
    _Float16*    Bpre      = (_Float16*)d_ws;   // 12*64*8*2 = 12 KB

    prep_b<<<12, 64, 0, stream>>>(W, Bpre);
    item_encoder<<<(32 * 128) / BNPB, 256, 0, stream>>>(item_type, item, emb, Bpre, bias, out);
}

// Round 6
// 89.491 us; speedup vs baseline: 1.3275x; 1.0177x over previous
//
#include <hip/hip_runtime.h>
#include <hip/hip_bf16.h>
#include <stdint.h>
#include <float.h>

// ItemEncoder: h = relu(concat(emb[type], item) @ W + b); out = max over item axis.
// BS=32, NA=128, NI=128, F=11, TH=32, K=43 (pad->48), NH=128.
//
// R6: latency-stall attack (R5 est. ~29 us vs ~5 us model floor):
//  - wave w owns ALL 128 rows of bn = bn0+w (4 row-blocks), max folded in registers
//    -> typs LDS, partial LDS, second barrier, phase-3 all deleted.
//  - ty read straight from global (coalesced); all 16 emb-gather float4s issued
//    into E[4][4] registers BEFORE the barrier -> every long-latency load is in
//    flight during the staging drain.
//  - row-block loop fully unrolled; static indexing throughout.
//  - prep_b unchanged: W -> f16 MFMA B-fragments in d_ws (12 KB), coalesced.

#define NITEM  128
#define NFEAT  11
#define NTH    32
#define NH     128
#define KREAL  43
#define KSTEPS 3            // K = 48 = 3 x 16
#define BNPB   4            // bn groups per block (one per wave)
#define SLABDW (NITEM * NFEAT)   // 1408 dwords per bn

typedef __attribute__((ext_vector_type(8)))  _Float16 half8;
typedef __attribute__((ext_vector_type(2)))  __fp16   fp16x2;   // cvt_pkrtz result type
typedef __attribute__((ext_vector_type(16))) float    f32x16;

union H8 { half8 h8; fp16x2 h2[4]; };

// ---- pre-kernel: build B fragments (frag = kk*4+n, 64 lanes each, half8/lane) ----
__global__ __launch_bounds__(64) void prep_b(const float* __restrict__ W,
                                             _Float16* __restrict__ Bpre) {
    const int frag = blockIdx.x;          // 0..11 = kk*4 + n
    const int kk   = frag >> 2;
    const int n    = frag & 3;
    const int lane = threadIdx.x;         // 0..63
    const int col  = n * 32 + (lane & 31);
    const int k0   = kk * 16 + (lane >> 5) * 8;
    half8 pk;
    #pragma unroll
    for (int q = 0; q < 8; ++q) {
        const int k = k0 + q;
        pk[q] = (_Float16)((k < KREAL) ? W[k * NH + col] : 0.0f);
    }
    ((half8*)Bpre)[frag * 64 + lane] = pk;
}

__global__ __launch_bounds__(256, 2) void item_encoder(
    const int*      __restrict__ item_type,  // [BS*NA*NI] int32
    const float*    __restrict__ item,       // [BS*NA*NI*NFEAT]
    const float*    __restrict__ emb,        // [18*32]
    const _Float16* __restrict__ Bpre,       // [12*64*8] f16 frags
    const float*    __restrict__ bias,       // [128]
    float*          __restrict__ out)        // [BS*NA*NH]
{
    __shared__ float slab[BNPB * SLABDW];        // 22528 B, raw f32 item feats

    const int t    = threadIdx.x;                // 0..255
    const int lane = t & 63;
    const int w    = t >> 6;
    const int l31  = lane & 31;
    const int lhi  = lane >> 5;
    const int bn0  = blockIdx.x * BNPB;
    const int bn   = bn0 + w;                    // this wave's bn group

    // ---- ty prefetch: 4 coalesced global int loads (no LDS round-trip) ----
    int ty[4];
    {
        const int* tb = item_type + (size_t)bn * NITEM + l31;
        #pragma unroll
        for (int rb = 0; rb < 4; ++rb) ty[rb] = tb[rb * 32];
    }

    // ---- block-wide coalesced staging of the 4 item slabs into LDS ----
    {
        const float4* gsl = (const float4*)(item + (size_t)bn0 * SLABDW);
        float4*       lsl = (float4*)slab;
        #pragma unroll
        for (int j = 0; j < 5; ++j) lsl[t + 256 * j] = gsl[t + 256 * j];  // 1280
        if (t < 128) lsl[1280 + t] = gsl[1280 + t];                       // 1408 total
    }

    // ---- B fragments: 12 coalesced 16B loads/lane (L2-resident after first wave) ----
    half8 bf[KSTEPS][4];
    #pragma unroll
    for (int kk = 0; kk < KSTEPS; ++kk)
        #pragma unroll
        for (int n = 0; n < 4; ++n)
            bf[kk][n] = ((const half8*)Bpre)[(kk * 4 + n) * 64 + lane];

    // ---- emb gathers for all 4 row-blocks, issued before the barrier ----
    // frag k-index: a0 -> k = lhi*8+q ; a1 -> k = 16+lhi*8+q (q=0..7)
    float4 E[4][4];
    #pragma unroll
    for (int rb = 0; rb < 4; ++rb) {
        const float* eb = emb + ty[rb] * NTH + lhi * 8;
        E[rb][0] = *(const float4*)(eb);
        E[rb][1] = *(const float4*)(eb + 4);
        E[rb][2] = *(const float4*)(eb + 16);
        E[rb][3] = *(const float4*)(eb + 20);
    }

    float bias4[4];
    #pragma unroll
    for (int n = 0; n < 4; ++n) bias4[n] = bias[n * 32 + l31];

    __syncthreads();

    // ---- per row-block: fv from LDS, cvt, 12 MFMA, fold max into vm[] ----
    float vm[4] = { -FLT_MAX, -FLT_MAX, -FLT_MAX, -FLT_MAX };

    #pragma unroll
    for (int rb = 0; rb < 4; ++rb) {
        const int r = rb * 32 + l31;
        const float* sp = slab + w * SLABDW + r * NFEAT;

        // feats f = lhi*8+q; f >= 11 -> 0 (stride-11 LDS reads, 2-way max = free)
        float fv[8];
        #pragma unroll
        for (int q = 0; q < 8; ++q) {
            const int  f  = lhi * 8 + q;
            const bool ok = (f < NFEAT);
            const float x = sp[ok ? f : 0];      // clamp addr, mask value
            fv[q] = ok ? x : 0.0f;
        }

        H8 a0, a1, a2;
        a0.h2[0] = __builtin_amdgcn_cvt_pkrtz(E[rb][0].x, E[rb][0].y);
        a0.h2[1] = __builtin_amdgcn_cvt_pkrtz(E[rb][0].z, E[rb][0].w);
        a0.h2[2] = __builtin_amdgcn_cvt_pkrtz(E[rb][1].x, E[rb][1].y);
        a0.h2[3] = __builtin_amdgcn_cvt_pkrtz(E[rb][1].z, E[rb][1].w);
        a1.h2[0] = __builtin_amdgcn_cvt_pkrtz(E[rb][2].x, E[rb][2].y);
        a1.h2[1] = __builtin_amdgcn_cvt_pkrtz(E[rb][2].z, E[rb][2].w);
        a1.h2[2] = __builtin_amdgcn_cvt_pkrtz(E[rb][3].x, E[rb][3].y);
        a1.h2[3] = __builtin_amdgcn_cvt_pkrtz(E[rb][3].z, E[rb][3].w);
        a2.h2[0] = __builtin_amdgcn_cvt_pkrtz(fv[0], fv[1]);
        a2.h2[1] = __builtin_amdgcn_cvt_pkrtz(fv[2], fv[3]);
        a2.h2[2] = __builtin_amdgcn_cvt_pkrtz(fv[4], fv[5]);
        a2.h2[3] = __builtin_amdgcn_cvt_pkrtz(fv[6], fv[7]);

        f32x16 acc[4];
        #pragma unroll
        for (int n = 0; n < 4; ++n)
            #pragma unroll
            for (int rr = 0; rr < 16; ++rr) acc[n][rr] = 0.0f;

        #pragma unroll
        for (int n = 0; n < 4; ++n) acc[n] = __builtin_amdgcn_mfma_f32_32x32x16_f16(a0.h8, bf[0][n], acc[n], 0, 0, 0);
        #pragma unroll
        for (int n = 0; n < 4; ++n) acc[n] = __builtin_amdgcn_mfma_f32_32x32x16_f16(a1.h8, bf[1][n], acc[n], 0, 0, 0);
        #pragma unroll
        for (int n = 0; n < 4; ++n) acc[n] = __builtin_amdgcn_mfma_f32_32x32x16_f16(a2.h8, bf[2][n], acc[n], 0, 0, 0);

        // max over this row-block's 32 rows, fold into running col-max
        // C/D layout: col = lane&31, row = (reg&3) + 8*(reg>>2) + 4*(lane>>5)
        #pragma unroll
        for (int n = 0; n < 4; ++n) {
            float m = acc[n][0];
            #pragma unroll
            for (int rr = 1; rr < 16; ++rr) m = fmaxf(m, acc[n][rr]);
            m = fmaxf(m, __shfl_xor(m, 32));     // fold the two 16-row halves
            vm[n] = fmaxf(vm[n], m);
        }
    }

    // ---- store: lanes 0..31 hold the 128-col result for this wave's bn ----
    if (lane < 32) {
        #pragma unroll
        for (int n = 0; n < 4; ++n)
            out[(size_t)bn * NH + n * 32 + l31] = fmaxf(vm[n] + bias4[n], 0.0f);
    }
}

extern "C" void kernel_launch(void* const* d_in, const int* in_sizes, int n_in,
                              void* d_out, int out_size, void* d_ws, size_t ws_size,
                              hipStream_t stream) {
    const int*   item_type = (const int*)  d_in[0];
    const float* item      = (const float*)d_in[1];
    const float* emb       = (const float*)d_in[2];
    const float* W         = (const float*)d_in[3];
    const float* bias      = (const float*)d_in[4];
    float*       out       = (float*)d_out;
    _Float16*    Bpre      = (_Float16*)d_ws;   // 12*64*8*2 = 12 KB

    prep_b<<<12, 64, 0, stream>>>(W, Bpre);
    item_encoder<<<(32 * 128) / BNPB, 256, 0, stream>>>(item_type, item, emb, Bpre, bias, out);
}